// Round 1
// baseline (89.146 us; speedup 1.0000x reference)
//
#include <hip/hip_runtime.h>

// SpikeLayer: per-pixel CDF over C=128 channels + S=128 searchsorted lookups.
// B=64, C=128, H=64, W=64, S=128. Output int32 channel indices [B,S,H,W].

#define BB 64
#define CC 128
#define HH 64
#define WW 64
#define SS 128

constexpr int PAD   = 129;         // LDS floats per pixel row (128 + 1 -> bank spread)
constexpr int GPAD  = 5;           // pad for group-total array
constexpr int GROUPS = 4;          // thread groups (along channel & spike dims)
constexpr int KPG   = CC / GROUPS; // 32 channels per group
constexpr int SPG   = SS / GROUPS; // 32 spikes per group

__global__ __launch_bounds__(256, 4) void spike_kernel(
    const float* __restrict__ inp,   // [B,C,H,W]
    const float* __restrict__ rnd,   // [B,S,H,W]
    int* __restrict__ out) {         // [B,S,H,W]
  __shared__ float cdf[WW * PAD];       // 64*129*4 = 33024 B
  __shared__ float gtot[WW * GPAD];     // group totals, 1280 B

  const int t = threadIdx.x;
  const int w = t & 63;    // pixel (w coordinate) — lane index -> coalesced
  const int g = t >> 6;    // group: wave-uniform
  const int bh = blockIdx.x;
  const int b = bh >> 6;   // / HH
  const int h = bh & 63;   // % HH

  // ---- phase 1: per-group sequential cumsum, kept in registers ----
  const float* ip = inp + (((size_t)b * CC + g * KPG) * HH + h) * WW + w;
  float vals[KPG];
  float run = 0.f;
#pragma unroll
  for (int k = 0; k < KPG; ++k) {
    run += ip[(size_t)k * (HH * WW)];
    vals[k] = run;
  }
  gtot[w * GPAD + g] = run;
  __syncthreads();

  // ---- phase 2: add prefix of earlier groups, write CDF to LDS ----
  float off = 0.f;
#pragma unroll
  for (int gg = 0; gg < GROUPS - 1; ++gg)
    if (gg < g) off += gtot[w * GPAD + gg];
#pragma unroll
  for (int k = 0; k < KPG; ++k)
    cdf[w * PAD + g * KPG + k] = vals[k] + off;
  __syncthreads();

  // ---- phase 3: binary search per spike ----
  const float total = cdf[w * PAD + (CC - 1)];  // unnormalized total; scale r by it
  const float* rp = rnd + (((size_t)b * SS + g * SPG) * HH + h) * WW + w;
  int*         op = out + (((size_t)b * SS + g * SPG) * HH + h) * WW + w;
  const int base_lds = w * PAD;

#pragma unroll 4
  for (int s = 0; s < SPG; ++s) {
    const float r = rp[(size_t)s * (HH * WW)] * total;
    int idx = 0;
    // lower_bound over 128 entries: idx = count(cdf < r), max 127 by construction
#pragma unroll
    for (int step = 64; step >= 1; step >>= 1) {
      const float v = cdf[base_lds + idx + (step - 1)];
      idx += (v < r) ? step : 0;
    }
    op[(size_t)s * (HH * WW)] = idx;
  }
}

extern "C" void kernel_launch(void* const* d_in, const int* in_sizes, int n_in,
                              void* d_out, int out_size, void* d_ws, size_t ws_size,
                              hipStream_t stream) {
  const float* inp = (const float*)d_in[0];  // "input"         [B,C,H,W] f32
  const float* rnd = (const float*)d_in[1];  // "random_values" [B,S,H,W] f32
  int* out = (int*)d_out;                    // int32 indices   [B,S,H,W]
  (void)in_sizes; (void)n_in; (void)out_size; (void)d_ws; (void)ws_size;

  spike_kernel<<<dim3(BB * HH), dim3(256), 0, stream>>>(inp, rnd, out);
}

// Round 2
// 88.941 us; speedup vs baseline: 1.0023x; 1.0023x over previous
//
#include <hip/hip_runtime.h>

// SpikeLayer: per-pixel CDF over C=128 channels + S=128 searchsorted lookups.
// B=64, C=128, H=64, W=64, S=128. Output int32 channel indices [B,S,H,W].
//
// R2: register-cached top 4 binary-search levels (15 values/thread) +
// single dependent LDS access per spike (2x independent ds_read_b128 of the
// final 8 candidates) + count-based finish. PAD=132 keeps rows 16B-aligned.

#define BB 64
#define CC 128
#define HH 64
#define WW 64
#define SS 128

constexpr int PAD    = 132;          // floats per pixel row (528 B, 16B-aligned)
constexpr int GROUPS = 4;            // thread groups (channel & spike split)
constexpr int KPG    = CC / GROUPS;  // 32 channels per group
constexpr int SPG    = SS / GROUPS;  // 32 spikes per group

__global__ __launch_bounds__(256, 4) void spike_kernel(
    const float* __restrict__ inp,   // [B,C,H,W]
    const float* __restrict__ rnd,   // [B,S,H,W]
    int* __restrict__ out) {         // [B,S,H,W]
  __shared__ float cdf[WW * PAD];       // 64*132*4 = 33792 B
  __shared__ float gtot[GROUPS * WW];   // 1024 B

  const int t = threadIdx.x;
  const int w = t & 63;    // pixel (w coordinate) — lane index -> coalesced
  const int g = t >> 6;    // group: wave-uniform
  const int bh = blockIdx.x;
  const int b = bh >> 6;   // / HH
  const int h = bh & 63;   // % HH
  const size_t HW = (size_t)HH * WW;

  // ---- phase 1: per-group sequential cumsum, kept in registers ----
  const float* ip = inp + ((size_t)b * CC + g * KPG) * HW + (size_t)h * WW + w;
  float vals[KPG];
  float run = 0.f;
#pragma unroll
  for (int k = 0; k < KPG; ++k) {
    run += ip[k * HW];
    vals[k] = run;
  }
  gtot[g * WW + w] = run;
  __syncthreads();

  // ---- phase 2: cross-group prefix + vectorized CDF write ----
  const float g0 = gtot[0 * WW + w], g1 = gtot[1 * WW + w];
  const float g2 = gtot[2 * WW + w], g3 = gtot[3 * WW + w];
  float off = 0.f;
  if (g > 0) off += g0;
  if (g > 1) off += g1;
  if (g > 2) off += g2;
  const float total = g0 + g1 + g2 + g3;   // unnormalized; scale r by it

  float4* crow = (float4*)&cdf[w * PAD + g * KPG];
#pragma unroll
  for (int j = 0; j < KPG / 4; ++j) {
    float4 v;
    v.x = vals[4 * j + 0] + off;
    v.y = vals[4 * j + 1] + off;
    v.z = vals[4 * j + 2] + off;
    v.w = vals[4 * j + 3] + off;
    crow[j] = v;
  }
  __syncthreads();

  // ---- phase 3: register-cached top levels, one LDS access per spike ----
  const int base = w * PAD;
  const float c63 = cdf[base + 63];
  const float c31 = cdf[base + 31], c95 = cdf[base + 95];
  const float c15 = cdf[base + 15], c47 = cdf[base + 47];
  const float c79 = cdf[base + 79], c111 = cdf[base + 111];
  const float c7  = cdf[base + 7],  c23 = cdf[base + 23];
  const float c39 = cdf[base + 39], c55 = cdf[base + 55];
  const float c71 = cdf[base + 71], c87 = cdf[base + 87];
  const float c103 = cdf[base + 103], c119 = cdf[base + 119];

  const float* rp = rnd + ((size_t)b * SS + g * SPG) * HW + (size_t)h * WW + w;
  int*         op = out + ((size_t)b * SS + g * SPG) * HW + (size_t)h * WW + w;

#pragma unroll 4
  for (int s = 0; s < SPG; ++s) {
    const float r = rp[s * HW] * total;
    // level 1 (step 64): probe cdf[63]
    const bool bl1 = c63 < r;
    // level 2 (step 32): probe cdf[idx+31]
    const float v2 = bl1 ? c95 : c31;
    const bool bl2 = v2 < r;
    // level 3 (step 16): probe cdf[idx+15]
    const float t3a = bl2 ? c47 : c15;
    const float t3b = bl2 ? c111 : c79;
    const float v3 = bl1 ? t3b : t3a;
    const bool bl3 = v3 < r;
    // level 4 (step 8): probe cdf[idx+7]
    const float t4a = bl3 ? c23 : c7;
    const float t4b = bl3 ? c55 : c39;
    const float t4c = bl3 ? c87 : c71;
    const float t4d = bl3 ? c119 : c103;
    const float u4a = bl2 ? t4b : t4a;
    const float u4b = bl2 ? t4d : t4c;
    const float v4 = bl1 ? u4b : u4a;
    const bool bl4 = v4 < r;
    int idx = (bl1 ? 64 : 0) + (bl2 ? 32 : 0) + (bl3 ? 16 : 0) + (bl4 ? 8 : 0);
    // final window [idx, idx+8): position = idx + count(cdf[idx..idx+6] < r)
    const float4 ca = *(const float4*)&cdf[base + idx];
    const float4 cb = *(const float4*)&cdf[base + idx + 4];
    const int cnt = (ca.x < r) + (ca.y < r) + (ca.z < r) + (ca.w < r)
                  + (cb.x < r) + (cb.y < r) + (cb.z < r);
    op[s * HW] = idx + cnt;
  }
}

extern "C" void kernel_launch(void* const* d_in, const int* in_sizes, int n_in,
                              void* d_out, int out_size, void* d_ws, size_t ws_size,
                              hipStream_t stream) {
  const float* inp = (const float*)d_in[0];  // "input"         [B,C,H,W] f32
  const float* rnd = (const float*)d_in[1];  // "random_values" [B,S,H,W] f32
  int* out = (int*)d_out;                    // int32 indices   [B,S,H,W]
  (void)in_sizes; (void)n_in; (void)out_size; (void)d_ws; (void)ws_size;

  spike_kernel<<<dim3(BB * HH), dim3(256), 0, stream>>>(inp, rnd, out);
}